// Round 13
// baseline (1019.738 us; speedup 1.0000x reference)
//
#include <hip/hip_runtime.h>

#define SEQ 4096
#define BATCH 512
#define INP 8
#define HID 30
#define LOG2E 1.44269504088896340736f

typedef float f32x2 __attribute__((ext_vector_type(2)));
typedef float f32x4 __attribute__((ext_vector_type(4)));
typedef unsigned uint2v __attribute__((ext_vector_type(2)));

#define RCP(v)  __builtin_amdgcn_rcpf(v)
#if __has_builtin(__builtin_amdgcn_exp2f)
#define EXP2(v) __builtin_amdgcn_exp2f(v)
#else
#define EXP2(v) exp2f(v)
#endif
#define PKFMA(a, b, c) __builtin_elementwise_fma(a, b, c)

__device__ __forceinline__ f32x2 mk2(float a, float b) {
    f32x2 r; r.x = a; r.y = b; return r;
}

// permlane32_swap with both operands = v:
//   returns {lo_rep = [v_lo32 | v_lo32], hi_rep = [v_hi32 | v_hi32]}
__device__ __forceinline__ void rep_halves(float v, float& lo_rep, float& hi_rep) {
#if __has_builtin(__builtin_amdgcn_permlane32_swap)
    uint2v r = __builtin_amdgcn_permlane32_swap(
        __float_as_uint(v), __float_as_uint(v), false, false);
    lo_rep = __uint_as_float(r.x);
    hi_rep = __uint_as_float(r.y);
#else
    float other = __shfl_xor(v, 32, 64);
    bool hi = (threadIdx.x & 32) != 0;
    lo_rep = hi ? other : v;
    hi_rep = hi ? v : other;
#endif
}

template <int CTRL>
__device__ __forceinline__ float dpp_sum_step(float v) {
    return v + __uint_as_float(__builtin_amdgcn_update_dpp(
        0, (int)__float_as_uint(v), CTRL, 0xf, 0xf, true));
}

// Sum within each 32-lane group, pure VALU. Total valid in lanes 15,31,47,63.
__device__ __forceinline__ float group32_reduce(float v) {
    v = dpp_sum_step<0x111>(v);  // row_shr:1
    v = dpp_sum_step<0x112>(v);  // row_shr:2
    v = dpp_sum_step<0x114>(v);  // row_shr:4
    v = dpp_sum_step<0x118>(v);  // row_shr:8
#if __has_builtin(__builtin_amdgcn_permlane16_swap)
    uint2v r = __builtin_amdgcn_permlane16_swap(
        __float_as_uint(v), __float_as_uint(v), false, false);
    return __uint_as_float(r.x) + __uint_as_float(r.y);
#else
    return v + __shfl_xor(v, 16, 64);
#endif
}

// One wave per batch chain (512 waves). Recurrence loop is VMEM-free (x staged
// through double-buffered LDS chunks of 64 steps). h broadcast via 30x
// v_readlane -> SGPR pairs feeding v_pk_fma_f32 directly (no LDS round trip
// on the critical chain). c2 update via one-product swap: each half computes
// m = Av*(half ? c2 : Bv2) locally; one permlane32_swap + add gives
// c2 = f*c2_prev + i*g*T2L on both halves. The Bv2 swap (for oT2) overlaps
// the c2->tanh chain. B-gate carries T2L folded (c2 = c*T2L state).
__global__ __launch_bounds__(64)
__attribute__((amdgpu_waves_per_eu(1, 1)))
void lstm_chain_kernel(
    const float* __restrict__ x,     // [SEQ,BATCH,INP]
    const float* __restrict__ W_ih,  // [4H, INP]
    const float* __restrict__ W_hh,  // [4H, HID]
    const float* __restrict__ b_ih,  // [4H]
    const float* __restrict__ b_hh,  // [4H]
    const float* __restrict__ W_lin, // [1, HID]
    const float* __restrict__ b_lin, // [1]
    float* __restrict__ out)         // [SEQ,BATCH,1]
{
    const int lane = threadIdx.x;
    // XCD-aware swizzle: consecutive chains share 64B x-lines / 32B out
    // sectors on one XCD's L2.
    const int g    = blockIdx.x;
    const int b    = (g & 7) * (BATCH / 8) + (g >> 3);
    const int j    = lane & 31;
    const int half = lane >> 5;
    const int jc   = j < HID ? j : HID - 1;
    const int ra   = half * HID + jc;            // i (half0) / f (half1): sigmoid
    const int rb   = 2 * HID + half * HID + jc;  // g (half0, tanh) / o (half1, sigmoid)

    // exp2 folding: sigmoid(v)=rcp(1+2^(-log2e*v)); tanh(v)=1-2*rcp(1+2^(2*log2e*v))
    const float sA   = -LOG2E;
    const float sB   = half ? -LOG2E : 2.0f * LOG2E;
    const float T2L  = 2.0f * LOG2E;            // tanh(c) via exp2(c*T2L)
    const float IT2L = 1.0f / (2.0f * LOG2E);
    // B-gate output pre-scaled by T2L: Bv2 = Bv * T2L (g*T2L on half0, o*T2L on half1)
    const float sclB2 = half ? T2L : -2.0f * T2L;
    const float addB2 = half ? 0.0f : T2L;

    // ---- packed per-lane weights, pre-scaled, pinned in VGPR pairs ----
    f32x2 wih2_a[INP / 2], wih2_b[INP / 2];
#pragma unroll
    for (int i = 0; i < INP / 2; ++i) {
        f32x2 wa = mk2(W_ih[ra * INP + 2 * i] * sA, W_ih[ra * INP + 2 * i + 1] * sA);
        f32x2 wb = mk2(W_ih[rb * INP + 2 * i] * sB, W_ih[rb * INP + 2 * i + 1] * sB);
        asm volatile("" : "+v"(wa));
        asm volatile("" : "+v"(wb));
        wih2_a[i] = wa;
        wih2_b[i] = wb;
    }
    f32x2 whh2_a[HID / 2], whh2_b[HID / 2];
#pragma unroll
    for (int k = 0; k < HID / 2; ++k) {
        f32x2 wa = mk2(W_hh[ra * HID + 2 * k] * sA, W_hh[ra * HID + 2 * k + 1] * sA);
        f32x2 wb = mk2(W_hh[rb * HID + 2 * k] * sB, W_hh[rb * HID + 2 * k + 1] * sB);
        asm volatile("" : "+v"(wa));
        asm volatile("" : "+v"(wb));
        whh2_a[k] = wa;
        whh2_b[k] = wb;
    }
    const float bias_sa = (b_ih[ra] + b_hh[ra]) * sA;
    const float bias_sb = (b_ih[rb] + b_hh[rb]) * sB;
    const float blin    = b_lin[0];
    const float wlin    = (j < HID) ? W_lin[j] : 0.0f;

    __shared__ float s_y[SEQ];
    __shared__ __align__(16) float s_x[2 * 64 * INP]; // 2 chunk buffers

    f32x4* sx4 = reinterpret_cast<f32x4*>(s_x);
    const f32x4* sx4c = reinterpret_cast<const f32x4*>(s_x);

    // h broadcast: wave-uniform values (readlane -> SGPRs)
    float hs[HID];
#pragma unroll
    for (int k = 0; k < HID; ++k) hs[k] = 0.0f;
    float c2 = 0.0f;  // carried state: c * T2L

    // ---- chunked x staging (vmcnt waits amortized to once per 64 steps) ----
    f32x4 stg0, stg1;

#define STAGELOAD(CH2) do {                                                   \
    int _b0 = (CH2) * 64 + (lane >> 1);                                       \
    int _b1 = _b0 + 32;                                                       \
    if (_b0 > SEQ - 1) _b0 = SEQ - 1;                                         \
    if (_b1 > SEQ - 1) _b1 = SEQ - 1;                                         \
    const f32x4* _p0 = (const f32x4*)(x + ((size_t)_b0 * BATCH + b) * INP) + (lane & 1); \
    const f32x4* _p1 = (const f32x4*)(x + ((size_t)_b1 * BATCH + b) * INP) + (lane & 1); \
    stg0 = *_p0;                                                              \
    stg1 = *_p1;                                                              \
} while (0)

#define STAGEWRITE(CHW) do {                                                  \
    f32x4* _d = sx4 + ((CHW) & 1) * 128;                                      \
    _d[lane]      = stg0;                                                     \
    _d[64 + lane] = stg1;                                                     \
} while (0)

#define LOADXL(XA, XB, TL) do {                                               \
    int _e = (((TL) >> 6) & 1) * 128 + ((TL) & 63) * 2;                       \
    XA = sx4c[_e];                                                            \
    XB = sx4c[_e + 1];                                                        \
} while (0)

    // rolling pre-activation (bias + W_ih·x) for the NEXT step
    f32x2 preA0, preA1, preB0, preB1;

#define IHPRE(XA, XB) do {                                                    \
    f32x2 x01 = __builtin_shufflevector(XA, XA, 0, 1);                        \
    f32x2 x23 = __builtin_shufflevector(XA, XA, 2, 3);                        \
    f32x2 x45 = __builtin_shufflevector(XB, XB, 0, 1);                        \
    f32x2 x67 = __builtin_shufflevector(XB, XB, 2, 3);                        \
    preA0 = mk2(bias_sa, 0.0f);  preB0 = mk2(bias_sb, 0.0f);                  \
    preA1 = mk2(0.0f, 0.0f);     preB1 = mk2(0.0f, 0.0f);                     \
    preA0 = PKFMA(x01, wih2_a[0], preA0);  preB0 = PKFMA(x01, wih2_b[0], preB0); \
    preA1 = PKFMA(x23, wih2_a[1], preA1);  preB1 = PKFMA(x23, wih2_b[1], preB1); \
    preA0 = PKFMA(x45, wih2_a[2], preA0);  preB0 = PKFMA(x45, wih2_b[2], preB0); \
    preA1 = PKFMA(x67, wih2_a[3], preA1);  preB1 = PKFMA(x67, wih2_b[3], preB1); \
} while (0)

    // prologue
    STAGELOAD(0);
    STAGEWRITE(0);
    STAGELOAD(1);

    f32x4 xA0, xB0, xA1, xB1, xA2, xB2, xA3, xB3;
    LOADXL(xA0, xB0, 0);  LOADXL(xA1, xB1, 1);
    LOADXL(xA2, xB2, 2);  LOADXL(xA3, xB3, 3);
    IHPRE(xA0, xB0);  // pre for t=0

// STEP(T, XAn/XBn: slot holding x[T+1] (feeds rolling pre),
//         XAl/XBl: slot to reload with x[TL=T+4])
#define STEP(T, XAn, XBn, XAl, XBl, TL) do {                                  \
    f32x2 A0 = preA0, A1 = preA1, B0 = preB0, B1 = preB1;                     \
    _Pragma("unroll")                                                         \
    for (int k = 0; k < HID / 2 - 1; k += 2) {                                \
        f32x2 h0 = mk2(hs[2*k],   hs[2*k+1]);                                 \
        f32x2 h1 = mk2(hs[2*k+2], hs[2*k+3]);                                 \
        A0 = PKFMA(h0, whh2_a[k],   A0);                                      \
        B0 = PKFMA(h0, whh2_b[k],   B0);                                      \
        A1 = PKFMA(h1, whh2_a[k+1], A1);                                      \
        B1 = PKFMA(h1, whh2_b[k+1], B1);                                      \
    }                                                                         \
    {                                                                         \
        f32x2 hT = mk2(hs[HID-2], hs[HID-1]);                                 \
        A0 = PKFMA(hT, whh2_a[HID/2-1], A0);                                  \
        B0 = PKFMA(hT, whh2_b[HID/2-1], B0);                                  \
    }                                                                         \
    f32x2 As = A0 + A1;  float ua = As.x + As.y;                              \
    f32x2 Bs = B0 + B1;  float ub = Bs.x + Bs.y;                              \
    float Av  = RCP(1.0f + EXP2(ua));     /* i (half0) / f (half1) */         \
    float sBv = RCP(1.0f + EXP2(ub));                                         \
    float Bv2 = fmaf(sBv, sclB2, addB2);  /* g*T2L (half0) / o*T2L (half1) */ \
    /* one-product swap: m = i*g*T2L (half0) | f*c2_prev (half1) */           \
    float m = Av * (half ? c2 : Bv2);                                         \
    float mlo, mhi;                                                           \
    rep_halves(m, mlo, mhi);                                                  \
    c2 = mlo + mhi;                       /* c*T2L, both halves */            \
    float glo, oT2;                                                           \
    rep_halves(Bv2, glo, oT2);            /* oT2 to both halves; || c2 chain */\
    float oo_u = oT2 * IT2L;                                                  \
    float n2o  = oT2 * (-2.0f * IT2L);                                        \
    float sc = RCP(1.0f + EXP2(c2));                                          \
    float h  = fmaf(sc, n2o, oo_u);       /* = o * tanh(c) */                 \
    _Pragma("unroll")                                                         \
    for (int k = 0; k < HID; ++k)                                             \
        hs[k] = __uint_as_float((unsigned)__builtin_amdgcn_readlane(          \
                    (int)__float_as_uint(h), k));                             \
    /* independent work fills readlane-issue gaps */                          \
    float p = group32_reduce(h * wlin);                                       \
    if (lane == 31) s_y[T] = p + blin;                                        \
    LOADXL(XAl, XBl, TL);                                                     \
    IHPRE(XAn, XBn);                                                          \
} while (0)

    for (int ch = 0; ch < SEQ / 64; ++ch) {
        STAGEWRITE(ch + 1);
        STAGELOAD(ch + 2);
        const int t0 = ch * 64;
#pragma unroll 1
        for (int tt = 0; tt < 64; tt += 4) {
            const int t = t0 + tt;
            STEP(t + 0, xA1, xB1, xA0, xB0, t + 4);
            STEP(t + 1, xA2, xB2, xA1, xB1, t + 5);
            STEP(t + 2, xA3, xB3, xA2, xB2, t + 6);
            STEP(t + 3, xA0, xB0, xA3, xB3, t + 7);
        }
    }
#undef STEP
#undef IHPRE
#undef LOADXL
#undef STAGELOAD
#undef STAGEWRITE

    // ---- dump y: 4096 floats, 16 iterations of (ds_read_b128 + 4 stores) ----
    __syncthreads();  // single wave; orders the last ds_write before reads
    const float4* s_y4 = reinterpret_cast<const float4*>(s_y);
#pragma unroll 4
    for (int it = 0; it < SEQ / 256; ++it) {
        int tbase = it * 256 + lane * 4;
        float4 v = s_y4[tbase >> 2];
        out[(size_t)(tbase + 0) * BATCH + b] = v.x;
        out[(size_t)(tbase + 1) * BATCH + b] = v.y;
        out[(size_t)(tbase + 2) * BATCH + b] = v.z;
        out[(size_t)(tbase + 3) * BATCH + b] = v.w;
    }
}

extern "C" void kernel_launch(void* const* d_in, const int* in_sizes, int n_in,
                              void* d_out, int out_size, void* d_ws, size_t ws_size,
                              hipStream_t stream) {
    const float* x     = (const float*)d_in[0];
    const float* W_ih  = (const float*)d_in[1];
    const float* W_hh  = (const float*)d_in[2];
    const float* b_ih  = (const float*)d_in[3];
    const float* b_hh  = (const float*)d_in[4];
    const float* W_lin = (const float*)d_in[5];
    const float* b_lin = (const float*)d_in[6];
    float* out = (float*)d_out;

    lstm_chain_kernel<<<dim3(BATCH), dim3(64), 0, stream>>>(
        x, W_ih, W_hh, b_ih, b_hh, W_lin, b_lin, out);
}

// Round 14
// 982.578 us; speedup vs baseline: 1.0378x; 1.0378x over previous
//
#include <hip/hip_runtime.h>

#define SEQ 4096
#define BATCH 512
#define INP 8
#define HID 30
#define LOG2E 1.44269504088896340736f

typedef float f32x2 __attribute__((ext_vector_type(2)));
typedef float f32x4 __attribute__((ext_vector_type(4)));
typedef unsigned uint2v __attribute__((ext_vector_type(2)));

#define RCP(v)  __builtin_amdgcn_rcpf(v)
#if __has_builtin(__builtin_amdgcn_exp2f)
#define EXP2(v) __builtin_amdgcn_exp2f(v)
#else
#define EXP2(v) exp2f(v)
#endif
#define PKFMA(a, b, c) __builtin_elementwise_fma(a, b, c)

__device__ __forceinline__ f32x2 mk2(float a, float b) {
    f32x2 r; r.x = a; r.y = b; return r;
}

// permlane32_swap with both operands = v:
//   returns {lo_rep = [v_lo32 | v_lo32], hi_rep = [v_hi32 | v_hi32]}
__device__ __forceinline__ void rep_halves(float v, float& lo_rep, float& hi_rep) {
#if __has_builtin(__builtin_amdgcn_permlane32_swap)
    uint2v r = __builtin_amdgcn_permlane32_swap(
        __float_as_uint(v), __float_as_uint(v), false, false);
    lo_rep = __uint_as_float(r.x);
    hi_rep = __uint_as_float(r.y);
#else
    float other = __shfl_xor(v, 32, 64);
    bool hi = (threadIdx.x & 32) != 0;
    lo_rep = hi ? other : v;
    hi_rep = hi ? v : other;
#endif
}

template <int CTRL>
__device__ __forceinline__ float dpp_sum_step(float v) {
    return v + __uint_as_float(__builtin_amdgcn_update_dpp(
        0, (int)__float_as_uint(v), CTRL, 0xf, 0xf, true));
}

// Sum within each 32-lane group, pure VALU. Total valid in lanes 15,31,47,63.
__device__ __forceinline__ float group32_reduce(float v) {
    v = dpp_sum_step<0x111>(v);  // row_shr:1
    v = dpp_sum_step<0x112>(v);  // row_shr:2
    v = dpp_sum_step<0x114>(v);  // row_shr:4
    v = dpp_sum_step<0x118>(v);  // row_shr:8
#if __has_builtin(__builtin_amdgcn_permlane16_swap)
    uint2v r = __builtin_amdgcn_permlane16_swap(
        __float_as_uint(v), __float_as_uint(v), false, false);
    return __uint_as_float(r.x) + __uint_as_float(r.y);
#else
    return v + __shfl_xor(v, 16, 64);
#endif
}

// One wave per batch chain (512 waves). Recurrence loop is VMEM-free (x staged
// through double-buffered LDS chunks of 64 steps). h broadcast via LDS round
// trip (covered by shadow work: DPP reduce, s_y store, LOADXL, rolling ih-pre).
// Matvec uses FOUR accumulators per gate side (dep depth 4+3 combine edges,
// was 8+2) -- the step is chain-latency-bound at ~8cy per dependent edge, so
// removing 3 edges is the lever. B-gate carries T2L folded (c2 = c*T2L state),
// h = fma(sc, n2o, oo_u) keeps the tail muls off-chain.
__global__ __launch_bounds__(64)
__attribute__((amdgpu_waves_per_eu(1, 1)))
void lstm_chain_kernel(
    const float* __restrict__ x,     // [SEQ,BATCH,INP]
    const float* __restrict__ W_ih,  // [4H, INP]
    const float* __restrict__ W_hh,  // [4H, HID]
    const float* __restrict__ b_ih,  // [4H]
    const float* __restrict__ b_hh,  // [4H]
    const float* __restrict__ W_lin, // [1, HID]
    const float* __restrict__ b_lin, // [1]
    float* __restrict__ out)         // [SEQ,BATCH,1]
{
    const int lane = threadIdx.x;
    // XCD-aware swizzle: consecutive chains share 64B x-lines / 32B out
    // sectors on one XCD's L2.
    const int g    = blockIdx.x;
    const int b    = (g & 7) * (BATCH / 8) + (g >> 3);
    const int j    = lane & 31;
    const int half = lane >> 5;
    const int jc   = j < HID ? j : HID - 1;
    const int ra   = half * HID + jc;            // i (half0) / f (half1): sigmoid
    const int rb   = 2 * HID + half * HID + jc;  // g (half0, tanh) / o (half1, sigmoid)

    // exp2 folding: sigmoid(v)=rcp(1+2^(-log2e*v)); tanh(v)=1-2*rcp(1+2^(2*log2e*v))
    const float sA   = -LOG2E;
    const float sB   = half ? -LOG2E : 2.0f * LOG2E;
    const float T2L  = 2.0f * LOG2E;            // tanh(c) via exp2(c*T2L)
    const float IT2L = 1.0f / (2.0f * LOG2E);
    // B-gate output pre-scaled by T2L: Bv2 = Bv * T2L
    const float sclB2 = half ? T2L : -2.0f * T2L;
    const float addB2 = half ? 0.0f : T2L;

    // ---- packed per-lane weights, pre-scaled, pinned in VGPR pairs ----
    f32x2 wih2_a[INP / 2], wih2_b[INP / 2];
#pragma unroll
    for (int i = 0; i < INP / 2; ++i) {
        f32x2 wa = mk2(W_ih[ra * INP + 2 * i] * sA, W_ih[ra * INP + 2 * i + 1] * sA);
        f32x2 wb = mk2(W_ih[rb * INP + 2 * i] * sB, W_ih[rb * INP + 2 * i + 1] * sB);
        asm volatile("" : "+v"(wa));
        asm volatile("" : "+v"(wb));
        wih2_a[i] = wa;
        wih2_b[i] = wb;
    }
    f32x2 whh2_a[HID / 2], whh2_b[HID / 2];
#pragma unroll
    for (int k = 0; k < HID / 2; ++k) {
        f32x2 wa = mk2(W_hh[ra * HID + 2 * k] * sA, W_hh[ra * HID + 2 * k + 1] * sA);
        f32x2 wb = mk2(W_hh[rb * HID + 2 * k] * sB, W_hh[rb * HID + 2 * k + 1] * sB);
        asm volatile("" : "+v"(wa));
        asm volatile("" : "+v"(wb));
        whh2_a[k] = wa;
        whh2_b[k] = wb;
    }
    const float bias_sa = (b_ih[ra] + b_hh[ra]) * sA;
    const float bias_sb = (b_ih[rb] + b_hh[rb]) * sB;
    const float blin    = b_lin[0];
    const float wlin    = (j < HID) ? W_lin[j] : 0.0f;

    __shared__ float s_y[SEQ];
    __shared__ __align__(16) float s_h[64];           // 0..29 valid; 30..63 dup
    __shared__ __align__(16) float s_x[2 * 64 * INP]; // 2 chunk buffers

    f32x4* sx4 = reinterpret_cast<f32x4*>(s_x);
    const f32x4* sx4c = reinterpret_cast<const f32x4*>(s_x);

    f32x2 hrf2[HID / 2];
#pragma unroll
    for (int k = 0; k < HID / 2; ++k) hrf2[k] = mk2(0.0f, 0.0f);
    float c2 = 0.0f;  // carried state: c * T2L

    // ---- chunked x staging (vmcnt waits amortized to once per 64 steps) ----
    f32x4 stg0, stg1;

#define STAGELOAD(CH2) do {                                                   \
    int _b0 = (CH2) * 64 + (lane >> 1);                                       \
    int _b1 = _b0 + 32;                                                       \
    if (_b0 > SEQ - 1) _b0 = SEQ - 1;                                         \
    if (_b1 > SEQ - 1) _b1 = SEQ - 1;                                         \
    const f32x4* _p0 = (const f32x4*)(x + ((size_t)_b0 * BATCH + b) * INP) + (lane & 1); \
    const f32x4* _p1 = (const f32x4*)(x + ((size_t)_b1 * BATCH + b) * INP) + (lane & 1); \
    stg0 = *_p0;                                                              \
    stg1 = *_p1;                                                              \
} while (0)

#define STAGEWRITE(CHW) do {                                                  \
    f32x4* _d = sx4 + ((CHW) & 1) * 128;                                      \
    _d[lane]      = stg0;                                                     \
    _d[64 + lane] = stg1;                                                     \
} while (0)

#define LOADXL(XA, XB, TL) do {                                               \
    int _e = (((TL) >> 6) & 1) * 128 + ((TL) & 63) * 2;                       \
    XA = sx4c[_e];                                                            \
    XB = sx4c[_e + 1];                                                        \
} while (0)

    // rolling pre-activation (bias + W_ih·x) for the NEXT step, 4 accs/side
    f32x2 preA0, preA1, preA2, preA3, preB0, preB1, preB2, preB3;

#define IHPRE(XA, XB) do {                                                    \
    f32x2 x01 = __builtin_shufflevector(XA, XA, 0, 1);                        \
    f32x2 x23 = __builtin_shufflevector(XA, XA, 2, 3);                        \
    f32x2 x45 = __builtin_shufflevector(XB, XB, 0, 1);                        \
    f32x2 x67 = __builtin_shufflevector(XB, XB, 2, 3);                        \
    preA0 = mk2(bias_sa, 0.0f);  preB0 = mk2(bias_sb, 0.0f);                  \
    preA0 = PKFMA(x01, wih2_a[0], preA0);  preB0 = PKFMA(x01, wih2_b[0], preB0); \
    preA1 = PKFMA(x23, wih2_a[1], mk2(0.0f, 0.0f));                           \
    preB1 = PKFMA(x23, wih2_b[1], mk2(0.0f, 0.0f));                           \
    preA2 = PKFMA(x45, wih2_a[2], mk2(0.0f, 0.0f));                           \
    preB2 = PKFMA(x45, wih2_b[2], mk2(0.0f, 0.0f));                           \
    preA3 = PKFMA(x67, wih2_a[3], mk2(0.0f, 0.0f));                           \
    preB3 = PKFMA(x67, wih2_b[3], mk2(0.0f, 0.0f));                           \
} while (0)

    // prologue
    STAGELOAD(0);
    STAGEWRITE(0);
    STAGELOAD(1);

    f32x4 xA0, xB0, xA1, xB1, xA2, xB2, xA3, xB3;
    LOADXL(xA0, xB0, 0);  LOADXL(xA1, xB1, 1);
    LOADXL(xA2, xB2, 2);  LOADXL(xA3, xB3, 3);
    IHPRE(xA0, xB0);  // pre for t=0

    const f32x4* s_h4 = reinterpret_cast<const f32x4*>(s_h);

// STEP(T, XAn/XBn: slot holding x[T+1] (feeds rolling pre),
//         XAl/XBl: slot to reload with x[TL=T+4])
#define STEP(T, XAn, XBn, XAl, XBl, TL) do {                                  \
    f32x2 A0 = preA0, A1 = preA1, A2 = preA2, A3 = preA3;                     \
    f32x2 B0 = preB0, B1 = preB1, B2 = preB2, B3 = preB3;                     \
    _Pragma("unroll")                                                         \
    for (int k = 0; k < 12; k += 4) {                                         \
        A0 = PKFMA(hrf2[k],   whh2_a[k],   A0);                               \
        B0 = PKFMA(hrf2[k],   whh2_b[k],   B0);                               \
        A1 = PKFMA(hrf2[k+1], whh2_a[k+1], A1);                               \
        B1 = PKFMA(hrf2[k+1], whh2_b[k+1], B1);                               \
        A2 = PKFMA(hrf2[k+2], whh2_a[k+2], A2);                               \
        B2 = PKFMA(hrf2[k+2], whh2_b[k+2], B2);                               \
        A3 = PKFMA(hrf2[k+3], whh2_a[k+3], A3);                               \
        B3 = PKFMA(hrf2[k+3], whh2_b[k+3], B3);                               \
    }                                                                         \
    A0 = PKFMA(hrf2[12], whh2_a[12], A0);  B0 = PKFMA(hrf2[12], whh2_b[12], B0); \
    A1 = PKFMA(hrf2[13], whh2_a[13], A1);  B1 = PKFMA(hrf2[13], whh2_b[13], B1); \
    A2 = PKFMA(hrf2[14], whh2_a[14], A2);  B2 = PKFMA(hrf2[14], whh2_b[14], B2); \
    f32x2 As = (A0 + A1) + (A2 + A3);                                         \
    f32x2 Bs = (B0 + B1) + (B2 + B3);                                         \
    float ua = As.x + As.y;                                                   \
    float ub = Bs.x + Bs.y;                                                   \
    float Av  = RCP(1.0f + EXP2(ua));                                         \
    float sBv = RCP(1.0f + EXP2(ub));                                         \
    float Bv2 = fmaf(sBv, sclB2, addB2);   /* B-gate output scaled by T2L */  \
    float ii, ff, gg2, oT2;                                                   \
    rep_halves(Av,  ii,  ff);                                                 \
    rep_halves(Bv2, gg2, oT2);             /* gg2 = g*T2L, oT2 = o*T2L */     \
    float oo_u = oT2 * IT2L;               /* off-chain */                    \
    float n2o  = oT2 * (-2.0f * IT2L);     /* off-chain */                    \
    c2 = fmaf(ff, c2, ii * gg2);           /* c2 = c*T2L */                   \
    float sc = RCP(1.0f + EXP2(c2));                                          \
    float h  = fmaf(sc, n2o, oo_u);        /* = o * tanh(c) */                \
    s_h[lane] = h;                         /* ds_write */                     \
    f32x4 hv0 = s_h4[0], hv1 = s_h4[1], hv2 = s_h4[2], hv3 = s_h4[3];         \
    f32x4 hv4 = s_h4[4], hv5 = s_h4[5], hv6 = s_h4[6], hv7 = s_h4[7];         \
    /* ---- read shadow: independent work ---- */                             \
    float p = group32_reduce(h * wlin);                                       \
    if (lane == 31) s_y[T] = p + blin;                                        \
    LOADXL(XAl, XBl, TL);                                                     \
    IHPRE(XAn, XBn);                                                          \
    /* ---- unpack broadcast for next step ---- */                            \
    hrf2[0]  = __builtin_shufflevector(hv0, hv0, 0, 1);                       \
    hrf2[1]  = __builtin_shufflevector(hv0, hv0, 2, 3);                       \
    hrf2[2]  = __builtin_shufflevector(hv1, hv1, 0, 1);                       \
    hrf2[3]  = __builtin_shufflevector(hv1, hv1, 2, 3);                       \
    hrf2[4]  = __builtin_shufflevector(hv2, hv2, 0, 1);                       \
    hrf2[5]  = __builtin_shufflevector(hv2, hv2, 2, 3);                       \
    hrf2[6]  = __builtin_shufflevector(hv3, hv3, 0, 1);                       \
    hrf2[7]  = __builtin_shufflevector(hv3, hv3, 2, 3);                       \
    hrf2[8]  = __builtin_shufflevector(hv4, hv4, 0, 1);                       \
    hrf2[9]  = __builtin_shufflevector(hv4, hv4, 2, 3);                       \
    hrf2[10] = __builtin_shufflevector(hv5, hv5, 0, 1);                       \
    hrf2[11] = __builtin_shufflevector(hv5, hv5, 2, 3);                       \
    hrf2[12] = __builtin_shufflevector(hv6, hv6, 0, 1);                       \
    hrf2[13] = __builtin_shufflevector(hv6, hv6, 2, 3);                       \
    hrf2[14] = __builtin_shufflevector(hv7, hv7, 0, 1);                       \
} while (0)

    for (int ch = 0; ch < SEQ / 64; ++ch) {
        STAGEWRITE(ch + 1);
        STAGELOAD(ch + 2);
        const int t0 = ch * 64;
#pragma unroll 1
        for (int tt = 0; tt < 64; tt += 4) {
            const int t = t0 + tt;
            STEP(t + 0, xA1, xB1, xA0, xB0, t + 4);
            STEP(t + 1, xA2, xB2, xA1, xB1, t + 5);
            STEP(t + 2, xA3, xB3, xA2, xB2, t + 6);
            STEP(t + 3, xA0, xB0, xA3, xB3, t + 7);
        }
    }
#undef STEP
#undef IHPRE
#undef LOADXL
#undef STAGELOAD
#undef STAGEWRITE

    // ---- dump y: 4096 floats, 16 iterations of (ds_read_b128 + 4 stores) ----
    __syncthreads();  // single wave; orders the last ds_write before reads
    const float4* s_y4 = reinterpret_cast<const float4*>(s_y);
#pragma unroll 4
    for (int it = 0; it < SEQ / 256; ++it) {
        int tbase = it * 256 + lane * 4;
        float4 v = s_y4[tbase >> 2];
        out[(size_t)(tbase + 0) * BATCH + b] = v.x;
        out[(size_t)(tbase + 1) * BATCH + b] = v.y;
        out[(size_t)(tbase + 2) * BATCH + b] = v.z;
        out[(size_t)(tbase + 3) * BATCH + b] = v.w;
    }
}

extern "C" void kernel_launch(void* const* d_in, const int* in_sizes, int n_in,
                              void* d_out, int out_size, void* d_ws, size_t ws_size,
                              hipStream_t stream) {
    const float* x     = (const float*)d_in[0];
    const float* W_ih  = (const float*)d_in[1];
    const float* W_hh  = (const float*)d_in[2];
    const float* b_ih  = (const float*)d_in[3];
    const float* b_hh  = (const float*)d_in[4];
    const float* W_lin = (const float*)d_in[5];
    const float* b_lin = (const float*)d_in[6];
    float* out = (float*)d_out;

    lstm_chain_kernel<<<dim3(BATCH), dim3(64), 0, stream>>>(
        x, W_ih, W_hh, b_ih, b_hh, W_lin, b_lin, out);
}